// Round 8
// baseline (501.454 us; speedup 1.0000x reference)
//
#include <hip/hip_runtime.h>

// ---------------------------------------------------------------------------
// RGAT encoder: N=50000, E=800000, R=8, IN=H=128, B=10.
// R16: fused softmax+pool+GEMM, relation-pair-split register pooling.
//      Lessons: R14 (8-lane rows = scatter, 2x worse), R15 (masked LDS RMW =
//      1/4 util, no gain). R16 pooling: wave = 4 groups x 16 lanes; group g
//      owns relations {2g,2g+1} (contiguous runs in (t,r)-CSR). Per edge:
//      one 16-lane x 16B coalesced row load (4 rows/wave-instr) + 8 unpack +
//      8 fma into REGISTER acc (full util, no RMW, no races: single writer
//      per As row, plain ds_write_b128 flush). Block = 512 thr / 16 targets
//      (2 per wave, serial); 37 KB LDS -> 4 blocks/CU. One barrier; wave wv
//      MFMAs ct=wv over K=1024 with B-frags from L2-hot WsT (R13-verified
//      tail). g round-trip + k_out deleted -> 12 dispatches total.
// ---------------------------------------------------------------------------

typedef unsigned int uint;
typedef unsigned short ushort_t;

using bf16x8 = __attribute__((ext_vector_type(8))) __bf16;
using f32x4  = __attribute__((ext_vector_type(4))) float;

__device__ __forceinline__ ushort_t fToBf(float f) {
  uint u = __float_as_uint(f);
  u += 0x7FFFu + ((u >> 16) & 1);   // round-to-nearest-even
  return (ushort_t)(u >> 16);
}
__device__ __forceinline__ float bfToF(ushort_t h) {
  return __uint_as_float(((uint)h) << 16);
}
__device__ __forceinline__ uint packBf(float a, float b) {
  return (uint)fToBf(a) | ((uint)fToBf(b) << 16);
}

// ------------------------------- CSR build ---------------------------------
// Segments keyed on t8r = tgt*8 + rel (400k segments); within a target the 8
// relation runs are contiguous ascending; softmax segment = [t*8, t*8+8).

__global__ void k_count2(const int* __restrict__ tgt, const int* __restrict__ et,
                         int* __restrict__ deg2, int E) {
  int e = blockIdx.x * 256 + threadIdx.x;
  if (e < E) atomicAdd(&deg2[tgt[e] * 8 + et[e]], 1);
}

__global__ void k_scanA(const int* __restrict__ deg, int* __restrict__ incl,
                        int* __restrict__ bsum, int n) {
  __shared__ int s[256];
  int tid = threadIdx.x;
  int i = blockIdx.x * 256 + tid;
  int v = (i < n) ? deg[i] : 0;
  s[tid] = v;
  __syncthreads();
  for (int off = 1; off < 256; off <<= 1) {
    int t = (tid >= off) ? s[tid - off] : 0;
    __syncthreads();
    s[tid] += t;
    __syncthreads();
  }
  if (i < n) incl[i] = s[tid];
  if (tid == 255) bsum[blockIdx.x] = s[255];
}

// single-block chunked exclusive scan of bsum[nb]
__global__ void k_scanB2(int* __restrict__ bsum, int nb) {
  __shared__ int s[256];
  __shared__ int carry;
  int tid = threadIdx.x;
  if (tid == 0) carry = 0;
  __syncthreads();
  for (int base = 0; base < nb; base += 256) {
    int i = base + tid;
    int v = (i < nb) ? bsum[i] : 0;
    s[tid] = v;
    __syncthreads();
    for (int off = 1; off < 256; off <<= 1) {
      int t = (tid >= off) ? s[tid - off] : 0;
      __syncthreads();
      s[tid] += t;
      __syncthreads();
    }
    int c = carry;
    if (i < nb) bsum[i] = c + s[tid] - v;   // exclusive
    __syncthreads();
    if (tid == 255) carry = c + s[255];
    __syncthreads();
  }
}

// writes rowptr AND the scatter cursor copy (absolute positions)
__global__ void k_scanC(const int* __restrict__ deg, const int* __restrict__ incl,
                        const int* __restrict__ bsum, int* __restrict__ rowptr,
                        int* __restrict__ cur, int n, int E) {
  int i = blockIdx.x * 256 + threadIdx.x;
  if (i < n) {
    int v = bsum[blockIdx.x] + incl[i] - deg[i];
    rowptr[i] = v;
    cur[i] = v;
    if (i == n - 1) rowptr[n] = E;
  }
}

__global__ void k_scatter2(const int* __restrict__ src, const int* __restrict__ tgt,
                           const int* __restrict__ et, int* __restrict__ cur,
                           int* __restrict__ sorted, int E) {
  int e = blockIdx.x * 256 + threadIdx.x;
  if (e >= E) return;
  int t8r = tgt[e] * 8 + et[e];
  int pos = atomicAdd(&cur[t8r], 1);        // absolute slot
  sorted[pos] = src[e] | (et[e] << 16);     // src < 65536, rel < 8
}

// ------------------------------ weight prep --------------------------------
// Merged: blocks 0..1023 build WsT[layer][r][n][k] = W[r][k][n] (B-frag rows);
// blocks 1024..1039 build wqk[layer][16][128] (rows 0..7 Wq[r], 8..15 Wk[r]).

__global__ void k_prep(const float* __restrict__ W1, const float* __restrict__ q1,
                       const float* __restrict__ k1, const float* __restrict__ W2,
                       const float* __restrict__ q2, const float* __restrict__ k2,
                       ushort_t* __restrict__ WsT, ushort_t* __restrict__ wqk) {
  int b = blockIdx.x;
  if (b < 1024) {
    int idx = b * 256 + threadIdx.x;           // ((l*8+r)*128 + k)*128 + n
    int n = idx & 127;
    int k = (idx >> 7) & 127;
    int rl = idx >> 14;                        // l*8 + r
    const float* W = (rl >> 3) ? W2 : W1;
    int r = rl & 7;
    float v = W[((size_t)r * 128 + k) * 128 + n];
    WsT[((size_t)rl * 128 + n) * 128 + k] = fToBf(v);
  } else {
    int g = (b - 1024) * 256 + threadIdx.x;    // 0..4095
    int layer = g >> 11;
    int which = (g >> 10) & 1;
    int idx = g & 1023;                        // r*128 + kin
    const float* w = (layer ? W2 : W1) + (size_t)idx * 128;
    const float* v = layer ? (which ? k2 : q2) : (which ? k1 : q1);
    float s = 0.f;
    #pragma unroll 8
    for (int hh = 0; hh < 128; hh++) s += w[hh] * v[hh];
    int r = idx >> 7, kin = idx & 127;
    wqk[(size_t)layer * 2048 + ((which << 3) + r) * 128 + kin] = fToBf(s);
  }
}

// ------------------------------- score pass --------------------------------
// stbl[node][16] = x[node] @ Wqk^T. F32IN additionally emits xb (bf16 cast).
// Fragment conventions (verified): A-frag m=lane&15, k=quad*8+j; B-frag
// n=lane&15, k=quad*8+j; C/D row=quad*4+reg, col=lane&15.

template <bool F32IN>
__global__ __launch_bounds__(256) void
k_score(const void* __restrict__ Ain,       // [M][128] f32 or bf16 node feats
        const ushort_t* __restrict__ Wqk,   // [16][128] this layer
        ushort_t* __restrict__ xb,          // [M][128] bf16 out (F32IN only)
        float* __restrict__ stbl,           // [M][16] out
        int M) {
  int tid = threadIdx.x, wv = tid >> 6, lane = tid & 63;
  int l15 = lane & 15, quad = lane >> 4;
  int node0 = blockIdx.x * 128 + wv * 32;

  bf16x8 bx[2][4];
  #pragma unroll
  for (int tile = 0; tile < 2; tile++) {
    int node = node0 + tile * 16 + l15;
    int nc = node < M ? node : M - 1;
    if (F32IN) {
      const float* row = (const float*)Ain + (size_t)nc * 128;
      #pragma unroll
      for (int kb = 0; kb < 4; kb++) {
        float4 a = *(const float4*)(row + kb * 32 + quad * 8);
        float4 b = *(const float4*)(row + kb * 32 + quad * 8 + 4);
        union { bf16x8 v; ushort_t u[8]; } t;
        t.u[0] = fToBf(a.x); t.u[1] = fToBf(a.y); t.u[2] = fToBf(a.z); t.u[3] = fToBf(a.w);
        t.u[4] = fToBf(b.x); t.u[5] = fToBf(b.y); t.u[6] = fToBf(b.z); t.u[7] = fToBf(b.w);
        bx[tile][kb] = t.v;
      }
    } else {
      const ushort_t* row = (const ushort_t*)Ain + (size_t)nc * 128;
      #pragma unroll
      for (int kb = 0; kb < 4; kb++)
        bx[tile][kb] = *(const bf16x8*)(row + kb * 32 + quad * 8);
    }
  }

  if (F32IN) {
    #pragma unroll
    for (int tile = 0; tile < 2; tile++) {
      int node = node0 + tile * 16 + l15;
      if (node < M) {
        #pragma unroll
        for (int kb = 0; kb < 4; kb++)
          *(bf16x8*)(xb + (size_t)node * 128 + kb * 32 + quad * 8) = bx[tile][kb];
      }
    }
  }

  bf16x8 aq[4];
  #pragma unroll
  for (int kb = 0; kb < 4; kb++)
    aq[kb] = *(const bf16x8*)(Wqk + (size_t)l15 * 128 + kb * 32 + quad * 8);
  #pragma unroll
  for (int tile = 0; tile < 2; tile++) {
    f32x4 s = {};
    #pragma unroll
    for (int kb = 0; kb < 4; kb++)
      s = __builtin_amdgcn_mfma_f32_16x16x32_bf16(aq[kb], bx[tile][kb], s, 0, 0, 0);
    int node = node0 + tile * 16 + l15;
    if (node < M) {
      float4 v = {s[0], s[1], s[2], s[3]};
      *(float4*)(stbl + (size_t)node * 16 + quad * 4) = v;
    }
  }
}

// ------------- fused softmax + pooled gather + output GEMM -----------------
// h[t] = relu( sum_r ( sum_{e in (t,r)} w_e x[src_e] ) @ W_r + b ).
// Block = 512 thr = 8 waves, 16 targets (2/wave, serial). Per target:
//   phase A (wave-wide): softmax; cache {pk, w/den} in s_pw (deg<=64 fast).
//   phase B (group-split): group g4=lane>>4 owns relations {2g4, 2g4+1};
//     walks each run with 8 f32 REGISTER accumulators, 2-wide unrolled
//     coalesced loads (16 lanes x 16B = full 256 B row; 4 rows/wave-instr);
//     flush = one ds_write_b128 per relation (single writer, no races).
// One barrier; wave wv MFMAs ct=wv (16 tgt x 16 ch, K=1024), B-frags from
// L2-resident WsT. Epilogue bias+relu -> h (standard order).
// Fragment conventions (verified): A-frag m=lane&15, k=quad*8+j; B-frag
// n=lane&15, k=quad*8+j; C/D row=quad*4+reg, col=lane&15.

#define LDK 1032   // As row stride in bf16 (2064 B: 16B-aligned, banks spread)

#define FMA8(ACC_, W_, V_)                                                \
  ACC_[0] = __builtin_fmaf(W_, bfToF((ushort_t)(V_.x & 0xFFFF)), ACC_[0]); \
  ACC_[1] = __builtin_fmaf(W_, bfToF((ushort_t)(V_.x >> 16)),    ACC_[1]); \
  ACC_[2] = __builtin_fmaf(W_, bfToF((ushort_t)(V_.y & 0xFFFF)), ACC_[2]); \
  ACC_[3] = __builtin_fmaf(W_, bfToF((ushort_t)(V_.y >> 16)),    ACC_[3]); \
  ACC_[4] = __builtin_fmaf(W_, bfToF((ushort_t)(V_.z & 0xFFFF)), ACC_[4]); \
  ACC_[5] = __builtin_fmaf(W_, bfToF((ushort_t)(V_.z >> 16)),    ACC_[5]); \
  ACC_[6] = __builtin_fmaf(W_, bfToF((ushort_t)(V_.w & 0xFFFF)), ACC_[6]); \
  ACC_[7] = __builtin_fmaf(W_, bfToF((ushort_t)(V_.w >> 16)),    ACC_[7]);

__global__ __launch_bounds__(512, 4) void
k_fused4(const ushort_t* __restrict__ feat,  // [M][128] bf16 node feats
         const float* __restrict__ stbl,     // [M][16]: 0..7 q-side, 8..15 k-side
         const int* __restrict__ rp2,        // [M*8+1]
         const int* __restrict__ sorted,     // src | (rel<<16), rel-sorted per t
         const ushort_t* __restrict__ WsT,   // [8][128][128] this layer
         const float* __restrict__ bias,
         ushort_t* __restrict__ h,           // [M][128] bf16 out
         int M) {
  __shared__ __align__(16) ushort_t As[16 * LDK];   // 33 KB
  __shared__ int2 s_pw[8][64];                      // {pk, bits(w/den)} 4 KB
  int tid = threadIdx.x, wv = tid >> 6, lane = tid & 63;
  int l15 = lane & 15, quad = lane >> 4;
  int g4 = lane >> 4, fcol = lane & 15;
  int t0 = blockIdx.x * 16;
  const uint4* fx4 = (const uint4*)feat;            // node row = 16 uint4

  for (int sub = 0; sub < 2; sub++) {
    int tl = wv * 2 + sub;                          // local target 0..15
    int t = t0 + tl;
    ushort_t* arow = As + (size_t)tl * LDK;
    if (t < M) {
      int e0 = rp2[t * 8], e1 = rp2[t * 8 + 8];
      int deg = e1 - e0;
      float m = -INFINITY, inv = 0.f;
      bool fast = (deg <= 64);

      // ---- phase A: softmax weights (wave-wide) ----
      if (fast) {
        float alpha = -INFINITY;
        int pk = 0;
        if (lane < deg) {
          pk = sorted[e0 + lane];
          int s = pk & 0xFFFF, r = pk >> 16;
          float a = stbl[(size_t)t * 16 + r] + stbl[(size_t)s * 16 + 8 + r];
          alpha = (a >= 0.f) ? a : 0.2f * a;        // leaky_relu 0.2
        }
        m = alpha;
        #pragma unroll
        for (int off = 32; off; off >>= 1) m = fmaxf(m, __shfl_xor(m, off, 64));
        float w = (lane < deg) ? __expf(alpha - m) : 0.f;
        float den = w;
        #pragma unroll
        for (int off = 32; off; off >>= 1) den += __shfl_xor(den, off, 64);
        inv = 1.f / (den + 1e-16f);
        int2 pw;
        pw.x = pk;
        pw.y = __float_as_int(w * inv);
        s_pw[wv][lane] = pw;
      } else {
        float den = 0.f;
        for (int base = e0; base < e1; base += 64) {
          int cnt = min(64, e1 - base);
          float alpha = -INFINITY;
          if (lane < cnt) {
            int pk = sorted[base + lane];
            int s = pk & 0xFFFF, r = pk >> 16;
            float a = stbl[(size_t)t * 16 + r] + stbl[(size_t)s * 16 + 8 + r];
            alpha = (a >= 0.f) ? a : 0.2f * a;
          }
          float cm = alpha;
          #pragma unroll
          for (int off = 32; off; off >>= 1) cm = fmaxf(cm, __shfl_xor(cm, off, 64));
          float nm = fmaxf(m, cm);
          float w = (lane < cnt) ? __expf(alpha - nm) : 0.f;
          float ws = w;
          #pragma unroll
          for (int off = 32; off; off >>= 1) ws += __shfl_xor(ws, off, 64);
          den = den * __expf(m - nm) + ws;
          m = nm;
        }
        inv = 1.f / (den + 1e-16f);
      }

      // ---- phase B: group g4 pools relations 2g4, 2g4+1 (register acc) ----
      int rbase = t * 8 + 2 * g4;
      int rs = rp2[rbase], rb = rp2[rbase + 1], re = rp2[rbase + 2];
      float tq0 = stbl[(size_t)t * 16 + 2 * g4];        // slow-path hoists
      float tq1 = stbl[(size_t)t * 16 + 2 * g4 + 1];

      #pragma unroll
      for (int half = 0; half < 2; half++) {
        int lo = half ? rb : rs;
        int hi = half ? re : rb;
        float tq = half ? tq1 : tq0;
        float acc[8] = {};
        if (fast) {
          int i = lo;
          for (; i + 1 < hi; i += 2) {                  // 2 rows in flight/group
            int2 pw0 = s_pw[wv][i - e0];
            int2 pw1 = s_pw[wv][i + 1 - e0];
            uint4 v0 = fx4[(size_t)(pw0.x & 0xFFFF) * 16 + fcol];
            uint4 v1 = fx4[(size_t)(pw1.x & 0xFFFF) * 16 + fcol];
            float w0 = __int_as_float(pw0.y);
            float w1 = __int_as_float(pw1.y);
            FMA8(acc, w0, v0)
            FMA8(acc, w1, v1)
          }
          if (i < hi) {
            int2 pw = s_pw[wv][i - e0];
            uint4 v = fx4[(size_t)(pw.x & 0xFFFF) * 16 + fcol];
            float w = __int_as_float(pw.y);
            FMA8(acc, w, v)
          }
        } else {
          for (int e = lo; e < hi; e++) {
            int pk = sorted[e];                          // group-uniform
            int s = pk & 0xFFFF;
            float a = tq + stbl[(size_t)s * 16 + 8 + (2 * g4 + half)];
            a = (a >= 0.f) ? a : 0.2f * a;
            float w = __expf(a - m) * inv;
            uint4 v = fx4[(size_t)s * 16 + fcol];
            FMA8(acc, w, v)
          }
        }
        uint4 o = {packBf(acc[0], acc[1]), packBf(acc[2], acc[3]),
                   packBf(acc[4], acc[5]), packBf(acc[6], acc[7])};
        *(uint4*)(arow + (2 * g4 + half) * 128 + fcol * 8) = o;
      }
    } else {
      uint4 z = {0, 0, 0, 0};
      *(uint4*)(arow + (2 * g4) * 128 + fcol * 8) = z;
      *(uint4*)(arow + (2 * g4 + 1) * 128 + fcol * 8) = z;
    }
  }
  __syncthreads();

  // ---- GEMM: wave wv computes ct = wv (16 targets x 16 cols), K = 1024 ----
  f32x4 dacc = {};
  #pragma unroll
  for (int r = 0; r < 8; r++) {
    const ushort_t* Wr = WsT + (size_t)r * 16384 + (size_t)(wv * 16 + l15) * 128;
    #pragma unroll
    for (int kb = 0; kb < 4; kb++) {
      bf16x8 afr = *(const bf16x8*)(As + (size_t)l15 * LDK + r * 128 + kb * 32 + quad * 8);
      bf16x8 bfr = *(const bf16x8*)(Wr + kb * 32 + quad * 8);
      dacc = __builtin_amdgcn_mfma_f32_16x16x32_bf16(afr, bfr, dacc, 0, 0, 0);
    }
  }

  // ---- epilogue: bias + relu -> bf16 ----
  float b = bias[wv * 16 + l15];
  #pragma unroll
  for (int reg = 0; reg < 4; reg++) {
    int rr = t0 + quad * 4 + reg;
    if (rr < M)
      h[(size_t)rr * 128 + wv * 16 + l15] = fToBf(fmaxf(dacc[reg] + b, 0.f));
  }
}

// ----------------------------- final linear --------------------------------

#define LDA 136

__global__ __launch_bounds__(256) void
k_gemmL(const ushort_t* __restrict__ A, const float* __restrict__ Wl,
        float* __restrict__ Cout, const float* __restrict__ bias, int M) {
  __shared__ ushort_t As[64 * LDA];
  __shared__ ushort_t Bs[128 * LDA];
  int tid = threadIdx.x;
  int row0 = blockIdx.x * 64;
  for (int c = tid; c < 1024; c += 256) {
    int r = c >> 4, off = (c & 15) * 8;
    int4 v = {0, 0, 0, 0};
    if (row0 + r < M) v = *(const int4*)(A + (size_t)(row0 + r) * 128 + off);
    *(int4*)(As + r * LDA + off) = v;
  }
  for (int c = tid; c < 2048; c += 256) {
    int nn = c >> 4, off = (c & 15) * 8;
    float4 a = *(const float4*)(Wl + (size_t)nn * 128 + off);
    float4 b = *(const float4*)(Wl + (size_t)nn * 128 + off + 4);
    ushort_t* d = Bs + nn * LDA + off;
    d[0] = fToBf(a.x); d[1] = fToBf(a.y); d[2] = fToBf(a.z); d[3] = fToBf(a.w);
    d[4] = fToBf(b.x); d[5] = fToBf(b.y); d[6] = fToBf(b.z); d[7] = fToBf(b.w);
  }
  __syncthreads();
  int wv = tid >> 6, lane = tid & 63;
  int l15 = lane & 15, quad = lane >> 4;
  int wr = wv * 16;
  bf16x8 afr[4];
  #pragma unroll
  for (int kb = 0; kb < 4; kb++)
    afr[kb] = *reinterpret_cast<const bf16x8*>(As + (wr + l15) * LDA + kb * 32 + quad * 8);
  f32x4 acc[8] = {};
  #pragma unroll
  for (int ct = 0; ct < 8; ct++)
    #pragma unroll
    for (int kb = 0; kb < 4; kb++) {
      bf16x8 bfr = *reinterpret_cast<const bf16x8*>(Bs + (ct * 16 + l15) * LDA + kb * 32 + quad * 8);
      acc[ct] = __builtin_amdgcn_mfma_f32_16x16x32_bf16(afr[kb], bfr, acc[ct], 0, 0, 0);
    }
  #pragma unroll
  for (int ct = 0; ct < 8; ct++)
    #pragma unroll
    for (int reg = 0; reg < 4; reg++) {
      int rr = row0 + wr + quad * 4 + reg;
      if (rr < M) Cout[(size_t)rr * 128 + ct * 16 + l15] = acc[ct][reg] + bias[ct * 16 + l15];
    }
}

// ------------------------------- launcher ----------------------------------

extern "C" void kernel_launch(void* const* d_in, const int* in_sizes, int n_in,
                              void* d_out, int out_size, void* d_ws, size_t ws_size,
                              hipStream_t stream) {
  const float* x   = (const float*)d_in[0];
  const int* ei    = (const int*)d_in[1];
  const int* etype = (const int*)d_in[2];
  const float* W1  = (const float*)d_in[4];
  const float* q1  = (const float*)d_in[5];
  const float* k1  = (const float*)d_in[6];
  const float* b1  = (const float*)d_in[7];
  const float* W2  = (const float*)d_in[8];
  const float* q2  = (const float*)d_in[9];
  const float* k2  = (const float*)d_in[10];
  const float* b2  = (const float*)d_in[11];
  const float* Wl  = (const float*)d_in[12];
  const float* bl  = (const float*)d_in[13];
  float* out       = (float*)d_out;

  const int N = in_sizes[0] / 128;   // 50000
  const int E = in_sizes[2];         // 800000

  char* ws = (char*)d_ws;
  size_t off = 0;
  auto alloc = [&](size_t bytes) {
    size_t o = off;
    off = (off + bytes + 255) & ~(size_t)255;
    return o;
  };

  ushort_t* h1    = (ushort_t*)(ws + alloc((size_t)N * 128 * 2));
  ushort_t* xbh2  = (ushort_t*)(ws + alloc((size_t)N * 128 * 2));    // xb then h2
  ushort_t* WsT   = (ushort_t*)(ws + alloc((size_t)2 * 8 * 16384 * 2));
  ushort_t* wqk   = (ushort_t*)(ws + alloc(2 * 16 * 128 * 2));
  float* stbl     = (float*)(ws + alloc((size_t)N * 16 * 4));
  int* deg2       = (int*)(ws + alloc((size_t)N * 8 * 4));
  int* cur2       = (int*)(ws + alloc((size_t)N * 8 * 4));
  int* incl2      = (int*)(ws + alloc((size_t)N * 8 * 4));
  int* rowptr2    = (int*)(ws + alloc((size_t)(N * 8 + 1) * 4));
  int* bsum       = (int*)(ws + alloc(2048 * 4));
  int* sorted     = (int*)(ws + alloc((size_t)E * 4));
  (void)ws_size; (void)n_in; (void)out_size;

  const int* srcp = ei;
  const int* tgtp = ei + E;

  int n2 = N * 8;                    // 400000 segments
  int gE  = (E + 255) / 256;
  int gN2 = (n2 + 255) / 256;        // 1563
  int gS  = (N + 127) / 128;         // k_score: 391
  int gF  = (N + 15) / 16;           // k_fused4: 3125 (512-thr blocks)
  int gL  = (N + 63) / 64;           // k_gemmL: 782

  // CSR build on (target, relation) segments (once; same graph both layers)
  hipMemsetAsync(deg2, 0, (size_t)n2 * 4, stream);
  k_count2<<<gE, 256, 0, stream>>>(tgtp, etype, deg2, E);
  k_scanA<<<gN2, 256, 0, stream>>>(deg2, incl2, bsum, n2);
  k_scanB2<<<1, 256, 0, stream>>>(bsum, gN2);
  k_scanC<<<gN2, 256, 0, stream>>>(deg2, incl2, bsum, rowptr2, cur2, n2, E);
  k_scatter2<<<gE, 256, 0, stream>>>(srcp, tgtp, etype, cur2, sorted, E);

  // weight prep (both layers, merged)
  k_prep<<<1040, 256, 0, stream>>>(W1, q1, k1, W2, q2, k2, WsT, wqk);

  // layer 1
  k_score<true><<<gS, 256, 0, stream>>>(x, wqk, xbh2, stbl, N);
  k_fused4<<<gF, 512, 0, stream>>>(xbh2, stbl, rowptr2, sorted, WsT, b1, h1, N);

  // layer 2 (xb buffer is dead after fused1; reused as h2 below)
  k_score<false><<<gS, 256, 0, stream>>>(h1, wqk + 2048, nullptr, stbl, N);
  k_fused4<<<gF, 512, 0, stream>>>(h1, stbl, rowptr2, sorted,
                                   WsT + (size_t)8 * 16384, b2, xbh2, N);

  // final linear
  k_gemmL<<<gL, 256, 0, stream>>>(xbh2, Wl, out, bl, N);
}